// Round 17
// baseline (42.727 us; speedup 1.0000x reference)
//
#include <hip/hip_runtime.h>
#include <cstdint>
#include <cstddef>

#define WD  50
#define MT  256
#define BSZ 4096
#define NCH 4                  // batch chunks: 1024 blocks of 4 waves
#define BCH (BSZ / NCH)        // 1024 rows per block
#define ITERS (BCH / 4 / 32)   // 8 iters per wave, 32 rows each

typedef __bf16 bf16x8 __attribute__((ext_vector_type(8)));
typedef float  f32x4  __attribute__((ext_vector_type(4)));

#define LOG2E 1.44269504088896340736f

__device__ __forceinline__ float swishf(float x) {
    // x * sigmoid(x) = x * rcp(1 + 2^(-x*log2e)); 5 instrs (2 trans)
    return x * __builtin_amdgcn_rcpf(1.0f + __builtin_amdgcn_exp2f(-LOG2E * x));
}
__device__ __forceinline__ unsigned short bfbits(float x) {
    union { __bf16 b; unsigned short s; } c; c.b = (__bf16)x; return c.s;
}
__device__ __forceinline__ float bfhi(unsigned u) { return __uint_as_float(u & 0xffff0000u); }
__device__ __forceinline__ float bflo(unsigned u) { return __uint_as_float(u << 16); }

// Fused 1->50->50->1 MLP, layer-2 on bf16 MFMA (16x16x32), one branch.
// ROUND-17: two 16-row groups per iteration, interleaved at FRAGMENT level
// (26 independent L1 swish chains, then 16 MFMAs sharing each W2 fragment,
// then both L3/reduce tails). W2 fragments are re-read from LDS inside the
// loop (8 ds_read_b128/iter, 2-way conflicts = free, amortized over both
// groups) — this frees wfrag's 32 VGPRs so the doubled acc/frag state fits
// the (256,4)=128 budget without spilling (r9's failure mode).
// b2 bf16-packed (r13: absmax-invisible); w3 stays f32 (packing costs 4e-3).
// Layout (r16-verified): LDS slot s=(kt*4+lgg)*8+e holds k=kt*32+e*4+lgg,
// byte-XOR s^((v&7)<<3); frag read vrow=vt*16+(lr&3)*4+(lr>>2);
// D: col=batch=lr, L3 slot s=vt*4+g -> v=s*4+lg; s=13..15 wave-uniform pad.
// MODE 0: out[m*BSZ + b]   MODE 1: out[(b*MT+m)*2+br]   MODE 2: out[b*MT+m]
template<int MODE>
__global__ __launch_bounds__(256, 4) void rmat_mlp_mfma(
    const float* __restrict__ U,
    const float* __restrict__ W1, const float* __restrict__ B1,
    const float* __restrict__ W2, const float* __restrict__ B2,
    const float* __restrict__ W3, const float* __restrict__ B3,
    float* __restrict__ out, int br)
{
    __shared__ __bf16 w2s[64 * 64];        // 8 KB

    const int m  = blockIdx.x >> 2;        // 0..255
    const int ch = blockIdx.x & 3;         // 0..3

    const float* __restrict__ w1 = W1 + m * WD;
    const float* __restrict__ b1 = B1 + m * WD;
    const float* __restrict__ w2 = W2 + (size_t)m * WD * WD;
    const float* __restrict__ b2 = B2 + m * WD;
    const float* __restrict__ w3 = W3 + m * WD;
    const float  b3v = B3[m];

    const int lane = threadIdx.x & 63;
    const int wid  = threadIdx.x >> 6;
    const int lr   = lane & 15;            // A-row index / D-col (batch)
    const int lg   = lane >> 4;            // k sub-slot / D-row group

    // ---- stage W2 -> LDS, coalesced reads, permuted+swizzled writes ----
    for (int idx = threadIdx.x; idx < 64 * 64; idx += 256) {
        const int v   = idx >> 6;
        const int s   = idx & 63;
        const int kt  = s >> 5;
        const int lgg = (s >> 3) & 3;
        const int e   = s & 7;
        const int k   = kt * 32 + e * 4 + lgg;
        const float w = (v < WD && k < WD) ? w2[v * WD + k] : 0.0f;
        w2s[(v << 6) + (s ^ ((v & 7) << 3))] = (__bf16)w;
    }

    // layer-1 weights: k = half*32 + e*4 + lg; half1 e>=5 is all-pad
    float w1v[13], b1v[13];
#pragma unroll
    for (int e = 0; e < 8; ++e) {
        const int k = e * 4 + lg;
        w1v[e] = w1[k];  b1v[e] = b1[k];
    }
#pragma unroll
    for (int e = 0; e < 5; ++e) {
        const int k = 32 + e * 4 + lg;
        w1v[8 + e] = (k < WD) ? w1[k] : 0.0f;
        b1v[8 + e] = (k < WD) ? b1[k] : 0.0f;
    }
    // layer-3: slot s -> v = s*4+lg; b2 bf16-packed pairs (8 regs), w3 f32
    unsigned b2p[8];
    float w3v[13];
#pragma unroll
    for (int h = 0; h < 8; ++h) {
        const int s0 = 2 * h;
        const int v0 = s0 * 4 + lg, v1 = (s0 + 1) * 4 + lg;
        const float f0 = (s0 < 13 && v0 < WD) ? b2[v0] : 0.0f;
        const float f1 = (s0 + 1 < 13 && v1 < WD) ? b2[v1] : 0.0f;
        b2p[h] = (unsigned)bfbits(f0) | ((unsigned)bfbits(f1) << 16);
    }
#pragma unroll
    for (int s = 0; s < 13; ++s) {
        const int v = s * 4 + lg;
        w3v[s] = (v < WD) ? w3[v] : 0.0f;
    }

    __syncthreads();

    // per-lane LDS fragment offsets: off[vt] for kt=0; kt=1 is off ^ 32
    int foff[4];
    const int vsub = ((lr & 3) << 2) + (lr >> 2);
#pragma unroll
    for (int vt = 0; vt < 4; ++vt) {
        const int vrow = vt * 16 + vsub;
        foff[vt] = (vrow << 6) + ((lg << 3) ^ ((vrow & 7) << 3));
    }

    float* __restrict__ dst = out + (size_t)m * BSZ;   // MODE 0 base
    const int b0 = ch * BCH + wid * (BCH / 4);         // wave's 256-row slice

#pragma unroll 1
    for (int it = 0; it < ITERS; ++it) {
        const int bb = b0 + it * 32;
        const float uA = U[bb + lr];
        const float uB = U[bb + 16 + lr];

        // layer 1, both groups: 26 independent swish chains
        bf16x8 xa0, xb0, xa1 = {}, xb1 = {};
#pragma unroll
        for (int e = 0; e < 8; ++e) {
            xa0[e] = (__bf16)swishf(fmaf(uA, w1v[e], b1v[e]));
            xb0[e] = (__bf16)swishf(fmaf(uB, w1v[e], b1v[e]));
        }
#pragma unroll
        for (int e = 0; e < 5; ++e) {
            xa1[e] = (__bf16)swishf(fmaf(uA, w1v[8 + e], b1v[8 + e]));
            xb1[e] = (__bf16)swishf(fmaf(uB, w1v[8 + e], b1v[8 + e]));
        }

        // layer 2: per vt read the two W2 fragments once, feed both groups
        f32x4 accA[4], accB[4];
#pragma unroll
        for (int vt = 0; vt < 4; ++vt) {
            const bf16x8 f0 = *reinterpret_cast<const bf16x8*>(&w2s[foff[vt]]);
            const bf16x8 f1 = *reinterpret_cast<const bf16x8*>(&w2s[foff[vt] ^ 32]);
            const f32x4 cin = {bflo(b2p[vt * 2]),     bfhi(b2p[vt * 2]),
                               bflo(b2p[vt * 2 + 1]), bfhi(b2p[vt * 2 + 1])};
            accA[vt] = __builtin_amdgcn_mfma_f32_16x16x32_bf16(f0, xa0, cin, 0, 0, 0);
            accA[vt] = __builtin_amdgcn_mfma_f32_16x16x32_bf16(f1, xa1, accA[vt], 0, 0, 0);
            accB[vt] = __builtin_amdgcn_mfma_f32_16x16x32_bf16(f0, xb0, cin, 0, 0, 0);
            accB[vt] = __builtin_amdgcn_mfma_f32_16x16x32_bf16(f1, xb1, accB[vt], 0, 0, 0);
        }

        // layer 3, both groups: 13 live slots each, then 2-step lg reduce
        float pa0 = 0.f, pa1 = 0.f, pa2 = 0.f, pa3 = 0.f;
        float pb0 = 0.f, pb1 = 0.f, pb2 = 0.f, pb3 = 0.f;
#pragma unroll
        for (int s = 0; s < 13; ++s) {
            const float ya = swishf(accA[s >> 2][s & 3]);
            const float yb = swishf(accB[s >> 2][s & 3]);
            if ((s & 3) == 0)      { pa0 = fmaf(w3v[s], ya, pa0); pb0 = fmaf(w3v[s], yb, pb0); }
            else if ((s & 3) == 1) { pa1 = fmaf(w3v[s], ya, pa1); pb1 = fmaf(w3v[s], yb, pb1); }
            else if ((s & 3) == 2) { pa2 = fmaf(w3v[s], ya, pa2); pb2 = fmaf(w3v[s], yb, pb2); }
            else                   { pa3 = fmaf(w3v[s], ya, pa3); pb3 = fmaf(w3v[s], yb, pb3); }
        }
        float pA = (pa0 + pa1) + (pa2 + pa3);
        float pB = (pb0 + pb1) + (pb2 + pb3);
        pA += __shfl_xor(pA, 16);
        pB += __shfl_xor(pB, 16);
        pA += __shfl_xor(pA, 32);
        pB += __shfl_xor(pB, 32);

        if (lane < 32) {                    // 32 rows stored by one wave
            const float vv = ((lane < 16) ? pA : pB) + b3v;
            const int row = bb + lane;
            if (MODE == 0)      dst[row] = vv;                 // 128B coalesced
            else if (MODE == 1) out[((size_t)row * MT + m) * 2 + br] = vv;
            else                out[(size_t)row * MT + m] = vv;
        }
    }
}

// ws[NBR][256][4096] -> out. NBR=2: [b][m][re,im]; NBR=1: transpose to [b][m].
// (Verbatim from the round-2/5/6 PASS.)
template<int NBR>
__global__ __launch_bounds__(256) void rmat_interleave(
    const float* __restrict__ ws, float* __restrict__ out)
{
    __shared__ float tile[NBR][32][64 + 1];
    const int bt = blockIdx.x & 63;
    const int mt = blockIdx.x >> 6;
    const int b0 = bt * 64, m0 = mt * 32;

    for (int i = threadIdx.x; i < NBR * 32 * 64; i += 256) {
        const int brx = i >> 11;           // 0 when NBR==1
        const int r   = (i >> 6) & 31;
        const int c   = i & 63;
        tile[brx][r][c] = ws[(size_t)(brx * MT + m0 + r) * BSZ + b0 + c];
    }
    __syncthreads();

    const int tb   = threadIdx.x >> 2;
    const int part = threadIdx.x & 3;
    const int b = b0 + tb;
    if (NBR == 2) {
        float2* __restrict__ dstp =
            reinterpret_cast<float2*>(out) + (size_t)b * MT + m0 + part * 8;
#pragma unroll
        for (int k = 0; k < 8; ++k) {
            const int mm = part * 8 + k;
            dstp[k] = make_float2(tile[0][mm][tb], tile[1][mm][tb]);
        }
    } else {
        float* __restrict__ dstp = out + (size_t)b * MT + m0 + part * 8;
#pragma unroll
        for (int k = 0; k < 8; ++k)
            dstp[k] = tile[0][part * 8 + k][tb];
    }
}

extern "C" void kernel_launch(void* const* d_in, const int* in_sizes, int n_in,
                              void* d_out, int out_size, void* d_ws, size_t ws_size,
                              hipStream_t stream) {
    const float* U   = (const float*)d_in[0];
    const float* W1r = (const float*)d_in[1];
    const float* b1r = (const float*)d_in[2];
    const float* W2r = (const float*)d_in[3];
    const float* b2r = (const float*)d_in[4];
    const float* W3r = (const float*)d_in[5];
    const float* b3r = (const float*)d_in[6];
    const float* W1i = (const float*)d_in[7];
    const float* b1i = (const float*)d_in[8];
    const float* W2i = (const float*)d_in[9];
    const float* b2i = (const float*)d_in[10];
    const float* W3i = (const float*)d_in[11];
    const float* b3i = (const float*)d_in[12];
    float* out = (float*)d_out;
    float* ws  = (float*)d_ws;

    const dim3 grid(MT * NCH), block(256);
    const size_t plane = (size_t)MT * BSZ;   // floats per branch

    if (out_size >= (int)(2 * plane)) {
        // d_out = [B][M] of (re,im) float pairs
        if (ws_size >= 2 * plane * sizeof(float)) {
            rmat_mlp_mfma<0><<<grid, block, 0, stream>>>(U, W1r, b1r, W2r, b2r, W3r, b3r, ws, 0);
            rmat_mlp_mfma<0><<<grid, block, 0, stream>>>(U, W1i, b1i, W2i, b2i, W3i, b3i, ws + plane, 1);
            rmat_interleave<2><<<dim3(512), block, 0, stream>>>(ws, out);
        } else {
            rmat_mlp_mfma<1><<<grid, block, 0, stream>>>(U, W1r, b1r, W2r, b2r, W3r, b3r, out, 0);
            rmat_mlp_mfma<1><<<grid, block, 0, stream>>>(U, W1i, b1i, W2i, b2i, W3i, b3i, out, 1);
        }
    } else {
        // d_out holds B*M float32 -> real branch only (harness drops imag)
        if (ws_size >= plane * sizeof(float)) {
            rmat_mlp_mfma<0><<<grid, block, 0, stream>>>(U, W1r, b1r, W2r, b2r, W3r, b3r, ws, 0);
            rmat_interleave<1><<<dim3(512), block, 0, stream>>>(ws, out);
        } else {
            rmat_mlp_mfma<2><<<grid, block, 0, stream>>>(U, W1r, b1r, W2r, b2r, W3r, b3r, out, 0);
        }
    }
}

// Round 18
// 42.665 us; speedup vs baseline: 1.0015x; 1.0015x over previous
//
#include <hip/hip_runtime.h>
#include <cstdint>
#include <cstddef>

#define WD  50
#define MT  256
#define BSZ 4096
#define NCH 8                  // batch chunks: 2048 blocks of 4 waves
#define BCH (BSZ / NCH)        // 512 rows per block
#define ITERS (BCH / 4 / 16)   // 8 iters per wave, 16 rows each

typedef __bf16 bf16x8 __attribute__((ext_vector_type(8)));
typedef float  f32x4  __attribute__((ext_vector_type(4)));

#define LOG2E 1.44269504088896340736f

__device__ __forceinline__ float swishf(float x) {
    // x * sigmoid(x) = x * rcp(1 + 2^(-x*log2e)); 5 instrs (2 trans)
    return x * __builtin_amdgcn_rcpf(1.0f + __builtin_amdgcn_exp2f(-LOG2E * x));
}

// Fused 1->50->50->1 MLP, layer-2 on bf16 MFMA (16x16x32), one branch.
// ROUND-18: r16 structure (coalesced LDS staging of W2, wfrag preloaded
// to registers via 8 ds_read_b128, 13+13 swish maps, b2 as C-in, 2-shfl
// reduce) + NCH=8 oversubscription + u-prefetch.
// Rationale: r17 closed the books on in-wave ILP (3 nulls, compiler
// serializes); busy ~= issue demand; the ~45% idle needs MORE RESIDENT
// WAVES. r8's oversubscription test was contaminated by the expensive
// scattered prologue (~5K cyc/wave); r16's staging is ~10x cheaper, so
// this is the clean residency experiment. VGPR=64 -> HW allows 8/SIMD.
// MODE 0: out[m*BSZ + b]   MODE 1: out[(b*MT+m)*2+br]   MODE 2: out[b*MT+m]
template<int MODE>
__global__ __launch_bounds__(256, 4) void rmat_mlp_mfma(
    const float* __restrict__ U,
    const float* __restrict__ W1, const float* __restrict__ B1,
    const float* __restrict__ W2, const float* __restrict__ B2,
    const float* __restrict__ W3, const float* __restrict__ B3,
    float* __restrict__ out, int br)
{
    __shared__ __bf16 w2s[64 * 64];        // 8 KB

    const int m  = blockIdx.x >> 3;        // 0..255
    const int ch = blockIdx.x & 7;         // 0..7

    const float* __restrict__ w1 = W1 + m * WD;
    const float* __restrict__ b1 = B1 + m * WD;
    const float* __restrict__ w2 = W2 + (size_t)m * WD * WD;
    const float* __restrict__ b2 = B2 + m * WD;
    const float* __restrict__ w3 = W3 + m * WD;
    const float  b3v = B3[m];

    const int lane = threadIdx.x & 63;
    const int wid  = threadIdx.x >> 6;
    const int lr   = lane & 15;            // A-row index / D-col (batch)
    const int lg   = lane >> 4;            // k sub-slot / D-row group

    // ---- stage W2 -> LDS, coalesced reads, permuted+swizzled writes ----
    // slot s = (kt*4+lgg)*8 + e holds k = kt*32 + e*4 + lgg (r15 k-map);
    // byte-level XOR swizzle: s ^= (v&7)<<3 (16B granule, G4 bank spread).
    for (int idx = threadIdx.x; idx < 64 * 64; idx += 256) {
        const int v   = idx >> 6;
        const int s   = idx & 63;
        const int kt  = s >> 5;
        const int lgg = (s >> 3) & 3;
        const int e   = s & 7;
        const int k   = kt * 32 + e * 4 + lgg;
        const float w = (v < WD && k < WD) ? w2[v * WD + k] : 0.0f;
        w2s[(v << 6) + (s ^ ((v & 7) << 3))] = (__bf16)w;
    }

    // layer-1 weights: k = half*32 + e*4 + lg; half1 e>=5 is all-pad
    float w1v[13], b1v[13];
#pragma unroll
    for (int e = 0; e < 8; ++e) {
        const int k = e * 4 + lg;
        w1v[e] = w1[k];  b1v[e] = b1[k];
    }
#pragma unroll
    for (int e = 0; e < 5; ++e) {
        const int k = 32 + e * 4 + lg;
        w1v[8 + e] = (k < WD) ? w1[k] : 0.0f;
        b1v[8 + e] = (k < WD) ? b1[k] : 0.0f;
    }
    // layer-3 constants: slot s -> v = s*4 + lg; s=13..15 dead (w3=b2=0)
    float b2v[16], w3v[13];
#pragma unroll
    for (int s = 0; s < 16; ++s) {
        const int v = s * 4 + lg;
        b2v[s] = (s < 13 && v < WD) ? b2[v] : 0.0f;
    }
#pragma unroll
    for (int s = 0; s < 13; ++s) {
        const int v = s * 4 + lg;
        w3v[s] = (v < WD) ? w3[v] : 0.0f;
    }

    __syncthreads();

    // ---- fill wfrag from LDS: 8 x ds_read_b128 per lane ----
    // A-row lr holds W2 row vrow = vt*16 + (lr&3)*4 + (lr>>2)
    bf16x8 wfrag[4][2];
    const int vsub = ((lr & 3) << 2) + (lr >> 2);
#pragma unroll
    for (int vt = 0; vt < 4; ++vt) {
        const int vrow = vt * 16 + vsub;
        const int base = vrow << 6;
        const int sw   = (vrow & 7) << 3;
#pragma unroll
        for (int kt = 0; kt < 2; ++kt) {
            const int off = base + ((((kt << 2) + lg) << 3) ^ sw);
            wfrag[vt][kt] = *reinterpret_cast<const bf16x8*>(&w2s[off]);
        }
    }

    float* __restrict__ dst = out + (size_t)m * BSZ;   // MODE 0 base
    const int b0 = ch * BCH + wid * (BCH / 4);         // wave's 128-row slice

    float u = U[b0 + lr];                  // prefetched first u
#pragma unroll 1
    for (int it = 0; it < ITERS; ++it) {
        const int bb = b0 + it * 16;
        // next iter's u issued early (clamped; last value unused)
        const float u_next = U[(bb + 16 + lr) & (BSZ - 1)];

        // layer 1 -> B fragments (batch col = lr); pad slots constant 0
        bf16x8 a0, a1 = {};
#pragma unroll
        for (int e = 0; e < 8; ++e)
            a0[e] = (__bf16)swishf(fmaf(u, w1v[e], b1v[e]));
#pragma unroll
        for (int e = 0; e < 5; ++e)
            a1[e] = (__bf16)swishf(fmaf(u, w1v[8 + e], b1v[8 + e]));

        // layer 2: D[v][batch]; b2 enters as C-in
        f32x4 acc[4];
#pragma unroll
        for (int vt = 0; vt < 4; ++vt) {
            acc[vt] = (f32x4){b2v[vt * 4 + 0], b2v[vt * 4 + 1],
                              b2v[vt * 4 + 2], b2v[vt * 4 + 3]};
            acc[vt] = __builtin_amdgcn_mfma_f32_16x16x32_bf16(wfrag[vt][0], a0, acc[vt], 0, 0, 0);
            acc[vt] = __builtin_amdgcn_mfma_f32_16x16x32_bf16(wfrag[vt][1], a1, acc[vt], 0, 0, 0);
        }

        // layer 3: 13 live slots, 4 chains, 2-step reduce over lg groups
        float pa = 0.0f, pb = 0.0f, pc = 0.0f, pd = 0.0f;
#pragma unroll
        for (int s = 0; s < 13; ++s) {
            const float y = swishf(acc[s >> 2][s & 3]);
            if ((s & 3) == 0)      pa = fmaf(w3v[s], y, pa);
            else if ((s & 3) == 1) pb = fmaf(w3v[s], y, pb);
            else if ((s & 3) == 2) pc = fmaf(w3v[s], y, pc);
            else                   pd = fmaf(w3v[s], y, pd);
        }
        float p = (pa + pb) + (pc + pd);
        p += __shfl_xor(p, 16);
        p += __shfl_xor(p, 32);

        u = u_next;

        if (lane < 16) {                    // lg==0: one result per batch col
            const int row = bb + lane;
            if (MODE == 0)      dst[row] = p + b3v;            // 64B/wave, coalesced
            else if (MODE == 1) out[((size_t)row * MT + m) * 2 + br] = p + b3v;
            else                out[(size_t)row * MT + m] = p + b3v;
        }
    }
}

// ws[NBR][256][4096] -> out. NBR=2: [b][m][re,im]; NBR=1: transpose to [b][m].
// (Verbatim from the round-2/5/6 PASS.)
template<int NBR>
__global__ __launch_bounds__(256) void rmat_interleave(
    const float* __restrict__ ws, float* __restrict__ out)
{
    __shared__ float tile[NBR][32][64 + 1];
    const int bt = blockIdx.x & 63;
    const int mt = blockIdx.x >> 6;
    const int b0 = bt * 64, m0 = mt * 32;

    for (int i = threadIdx.x; i < NBR * 32 * 64; i += 256) {
        const int brx = i >> 11;           // 0 when NBR==1
        const int r   = (i >> 6) & 31;
        const int c   = i & 63;
        tile[brx][r][c] = ws[(size_t)(brx * MT + m0 + r) * BSZ + b0 + c];
    }
    __syncthreads();

    const int tb   = threadIdx.x >> 2;
    const int part = threadIdx.x & 3;
    const int b = b0 + tb;
    if (NBR == 2) {
        float2* __restrict__ dstp =
            reinterpret_cast<float2*>(out) + (size_t)b * MT + m0 + part * 8;
#pragma unroll
        for (int k = 0; k < 8; ++k) {
            const int mm = part * 8 + k;
            dstp[k] = make_float2(tile[0][mm][tb], tile[1][mm][tb]);
        }
    } else {
        float* __restrict__ dstp = out + (size_t)b * MT + m0 + part * 8;
#pragma unroll
        for (int k = 0; k < 8; ++k)
            dstp[k] = tile[0][part * 8 + k][tb];
    }
}

extern "C" void kernel_launch(void* const* d_in, const int* in_sizes, int n_in,
                              void* d_out, int out_size, void* d_ws, size_t ws_size,
                              hipStream_t stream) {
    const float* U   = (const float*)d_in[0];
    const float* W1r = (const float*)d_in[1];
    const float* b1r = (const float*)d_in[2];
    const float* W2r = (const float*)d_in[3];
    const float* b2r = (const float*)d_in[4];
    const float* W3r = (const float*)d_in[5];
    const float* b3r = (const float*)d_in[6];
    const float* W1i = (const float*)d_in[7];
    const float* b1i = (const float*)d_in[8];
    const float* W2i = (const float*)d_in[9];
    const float* b2i = (const float*)d_in[10];
    const float* W3i = (const float*)d_in[11];
    const float* b3i = (const float*)d_in[12];
    float* out = (float*)d_out;
    float* ws  = (float*)d_ws;

    const dim3 grid(MT * NCH), block(256);
    const size_t plane = (size_t)MT * BSZ;   // floats per branch

    if (out_size >= (int)(2 * plane)) {
        // d_out = [B][M] of (re,im) float pairs
        if (ws_size >= 2 * plane * sizeof(float)) {
            rmat_mlp_mfma<0><<<grid, block, 0, stream>>>(U, W1r, b1r, W2r, b2r, W3r, b3r, ws, 0);
            rmat_mlp_mfma<0><<<grid, block, 0, stream>>>(U, W1i, b1i, W2i, b2i, W3i, b3i, ws + plane, 1);
            rmat_interleave<2><<<dim3(512), block, 0, stream>>>(ws, out);
        } else {
            rmat_mlp_mfma<1><<<grid, block, 0, stream>>>(U, W1r, b1r, W2r, b2r, W3r, b3r, out, 0);
            rmat_mlp_mfma<1><<<grid, block, 0, stream>>>(U, W1i, b1i, W2i, b2i, W3i, b3i, out, 1);
        }
    } else {
        // d_out holds B*M float32 -> real branch only (harness drops imag)
        if (ws_size >= plane * sizeof(float)) {
            rmat_mlp_mfma<0><<<grid, block, 0, stream>>>(U, W1r, b1r, W2r, b2r, W3r, b3r, ws, 0);
            rmat_interleave<1><<<dim3(512), block, 0, stream>>>(ws, out);
        } else {
            rmat_mlp_mfma<2><<<grid, block, 0, stream>>>(U, W1r, b1r, W2r, b2r, W3r, b3r, out, 0);
        }
    }
}

// Round 19
// 38.762 us; speedup vs baseline: 1.1023x; 1.1007x over previous
//
#include <hip/hip_runtime.h>
#include <cstdint>
#include <cstddef>

#define WD  50
#define MT  256
#define BSZ 4096
#define NCH 4                  // batch chunks: 1024 blocks of 4 waves
#define BCH (BSZ / NCH)        // 1024 rows per block
#define ITERS (BCH / 4 / 16)   // 16 iters per wave, 16 rows each

typedef __bf16 bf16x8 __attribute__((ext_vector_type(8)));
typedef float  f32x4  __attribute__((ext_vector_type(4)));

#define LOG2E 1.44269504088896340736f

__device__ __forceinline__ float swishf(float x) {
    // x * sigmoid(x) = x * rcp(1 + 2^(-x*log2e)); 5 instrs (2 trans)
    return x * __builtin_amdgcn_rcpf(1.0f + __builtin_amdgcn_exp2f(-LOG2E * x));
}

// Fused 1->50->50->1 MLP, layer-2 on bf16 MFMA (16x16x32), one branch.
// ROUND-19: r16 structure unchanged (coalesced LDS staging of W2, wfrag
// in registers via 8 ds_read_b128, 13+13 swish maps, b2 as C-in, 2-shfl
// reduce) — but the single-component output path now stores DIRECTLY to
// out[b*MT+m] (MODE 2), eliminating the interleave dispatch and the 8 MB
// ws round-trip. Scattered 4B stores are fire-and-forget; the kernel has
// ~45% idle issue slots to hide them; L2 merges partial lines (4 MB dirty
// total, same as before).
// Occupancy post-mortem (r8-r18): resident waves pinned ~3/SIMD by the
// unified VGPR+AGPR live total (~150); every cap attempt spills (r7/r13/
// r14), every grid/ILP/pipeline attempt is null (r8/r9/r12/r15/r17/r18).
// Busy ~= issue floor (~23us); this round removes the last overhead.
// MODE 0: out[m*BSZ + b]   MODE 1: out[(b*MT+m)*2+br]   MODE 2: out[b*MT+m]
template<int MODE>
__global__ __launch_bounds__(256, 4) void rmat_mlp_mfma(
    const float* __restrict__ U,
    const float* __restrict__ W1, const float* __restrict__ B1,
    const float* __restrict__ W2, const float* __restrict__ B2,
    const float* __restrict__ W3, const float* __restrict__ B3,
    float* __restrict__ out, int br)
{
    __shared__ __bf16 w2s[64 * 64];        // 8 KB

    const int m  = blockIdx.x >> 2;        // 0..255
    const int ch = blockIdx.x & 3;         // 0..3

    const float* __restrict__ w1 = W1 + m * WD;
    const float* __restrict__ b1 = B1 + m * WD;
    const float* __restrict__ w2 = W2 + (size_t)m * WD * WD;
    const float* __restrict__ b2 = B2 + m * WD;
    const float* __restrict__ w3 = W3 + m * WD;
    const float  b3v = B3[m];

    const int lane = threadIdx.x & 63;
    const int wid  = threadIdx.x >> 6;
    const int lr   = lane & 15;            // A-row index / D-col (batch)
    const int lg   = lane >> 4;            // k sub-slot / D-row group

    // ---- stage W2 -> LDS, coalesced reads, permuted+swizzled writes ----
    // slot s = (kt*4+lgg)*8 + e holds k = kt*32 + e*4 + lgg (r15 k-map);
    // byte-level XOR swizzle: s ^= (v&7)<<3 (16B granule, G4 bank spread).
    for (int idx = threadIdx.x; idx < 64 * 64; idx += 256) {
        const int v   = idx >> 6;
        const int s   = idx & 63;
        const int kt  = s >> 5;
        const int lgg = (s >> 3) & 3;
        const int e   = s & 7;
        const int k   = kt * 32 + e * 4 + lgg;
        const float w = (v < WD && k < WD) ? w2[v * WD + k] : 0.0f;
        w2s[(v << 6) + (s ^ ((v & 7) << 3))] = (__bf16)w;
    }

    // layer-1 weights: k = half*32 + e*4 + lg; half1 e>=5 is all-pad
    float w1v[13], b1v[13];
#pragma unroll
    for (int e = 0; e < 8; ++e) {
        const int k = e * 4 + lg;
        w1v[e] = w1[k];  b1v[e] = b1[k];
    }
#pragma unroll
    for (int e = 0; e < 5; ++e) {
        const int k = 32 + e * 4 + lg;
        w1v[8 + e] = (k < WD) ? w1[k] : 0.0f;
        b1v[8 + e] = (k < WD) ? b1[k] : 0.0f;
    }
    // layer-3 constants: slot s -> v = s*4 + lg; s=13..15 dead (w3=b2=0)
    float b2v[16], w3v[13];
#pragma unroll
    for (int s = 0; s < 16; ++s) {
        const int v = s * 4 + lg;
        b2v[s] = (s < 13 && v < WD) ? b2[v] : 0.0f;
    }
#pragma unroll
    for (int s = 0; s < 13; ++s) {
        const int v = s * 4 + lg;
        w3v[s] = (v < WD) ? w3[v] : 0.0f;
    }

    __syncthreads();

    // ---- fill wfrag from LDS: 8 x ds_read_b128 per lane ----
    // A-row lr holds W2 row vrow = vt*16 + (lr&3)*4 + (lr>>2)
    bf16x8 wfrag[4][2];
    const int vsub = ((lr & 3) << 2) + (lr >> 2);
#pragma unroll
    for (int vt = 0; vt < 4; ++vt) {
        const int vrow = vt * 16 + vsub;
        const int base = vrow << 6;
        const int sw   = (vrow & 7) << 3;
#pragma unroll
        for (int kt = 0; kt < 2; ++kt) {
            const int off = base + ((((kt << 2) + lg) << 3) ^ sw);
            wfrag[vt][kt] = *reinterpret_cast<const bf16x8*>(&w2s[off]);
        }
    }

    float* __restrict__ dst = out + (size_t)m * BSZ;   // MODE 0 base
    const int b0 = ch * BCH + wid * (BCH / 4);         // wave's 256-row slice

#pragma unroll 1
    for (int it = 0; it < ITERS; ++it) {
        const int bb = b0 + it * 16;
        const float u = U[bb + lr];

        // layer 1 -> B fragments (batch col = lr); pad slots constant 0
        bf16x8 a0, a1 = {};
#pragma unroll
        for (int e = 0; e < 8; ++e)
            a0[e] = (__bf16)swishf(fmaf(u, w1v[e], b1v[e]));
#pragma unroll
        for (int e = 0; e < 5; ++e)
            a1[e] = (__bf16)swishf(fmaf(u, w1v[8 + e], b1v[8 + e]));

        // layer 2: D[v][batch]; b2 enters as C-in
        f32x4 acc[4];
#pragma unroll
        for (int vt = 0; vt < 4; ++vt) {
            acc[vt] = (f32x4){b2v[vt * 4 + 0], b2v[vt * 4 + 1],
                              b2v[vt * 4 + 2], b2v[vt * 4 + 3]};
            acc[vt] = __builtin_amdgcn_mfma_f32_16x16x32_bf16(wfrag[vt][0], a0, acc[vt], 0, 0, 0);
            acc[vt] = __builtin_amdgcn_mfma_f32_16x16x32_bf16(wfrag[vt][1], a1, acc[vt], 0, 0, 0);
        }

        // layer 3: 13 live slots, 4 chains, 2-step reduce over lg groups
        float pa = 0.0f, pb = 0.0f, pc = 0.0f, pd = 0.0f;
#pragma unroll
        for (int s = 0; s < 13; ++s) {
            const float y = swishf(acc[s >> 2][s & 3]);
            if ((s & 3) == 0)      pa = fmaf(w3v[s], y, pa);
            else if ((s & 3) == 1) pb = fmaf(w3v[s], y, pb);
            else if ((s & 3) == 2) pc = fmaf(w3v[s], y, pc);
            else                   pd = fmaf(w3v[s], y, pd);
        }
        float p = (pa + pb) + (pc + pd);
        p += __shfl_xor(p, 16);
        p += __shfl_xor(p, 32);

        if (lane < 16) {                    // lg==0: one result per batch col
            const int row = bb + lane;
            if (MODE == 0)      dst[row] = p + b3v;            // 64B/wave, coalesced
            else if (MODE == 1) out[((size_t)row * MT + m) * 2 + br] = p + b3v;
            else                out[(size_t)row * MT + m] = p + b3v;  // direct scatter
        }
    }
}

// ws[NBR][256][4096] -> out. NBR=2: [b][m][re,im]; NBR=1: transpose to [b][m].
// (Verbatim from the round-2/5/6 PASS; only used in the 2M-output path now.)
template<int NBR>
__global__ __launch_bounds__(256) void rmat_interleave(
    const float* __restrict__ ws, float* __restrict__ out)
{
    __shared__ float tile[NBR][32][64 + 1];
    const int bt = blockIdx.x & 63;
    const int mt = blockIdx.x >> 6;
    const int b0 = bt * 64, m0 = mt * 32;

    for (int i = threadIdx.x; i < NBR * 32 * 64; i += 256) {
        const int brx = i >> 11;           // 0 when NBR==1
        const int r   = (i >> 6) & 31;
        const int c   = i & 63;
        tile[brx][r][c] = ws[(size_t)(brx * MT + m0 + r) * BSZ + b0 + c];
    }
    __syncthreads();

    const int tb   = threadIdx.x >> 2;
    const int part = threadIdx.x & 3;
    const int b = b0 + tb;
    if (NBR == 2) {
        float2* __restrict__ dstp =
            reinterpret_cast<float2*>(out) + (size_t)b * MT + m0 + part * 8;
#pragma unroll
        for (int k = 0; k < 8; ++k) {
            const int mm = part * 8 + k;
            dstp[k] = make_float2(tile[0][mm][tb], tile[1][mm][tb]);
        }
    } else {
        float* __restrict__ dstp = out + (size_t)b * MT + m0 + part * 8;
#pragma unroll
        for (int k = 0; k < 8; ++k)
            dstp[k] = tile[0][part * 8 + k][tb];
    }
}

extern "C" void kernel_launch(void* const* d_in, const int* in_sizes, int n_in,
                              void* d_out, int out_size, void* d_ws, size_t ws_size,
                              hipStream_t stream) {
    const float* U   = (const float*)d_in[0];
    const float* W1r = (const float*)d_in[1];
    const float* b1r = (const float*)d_in[2];
    const float* W2r = (const float*)d_in[3];
    const float* b2r = (const float*)d_in[4];
    const float* W3r = (const float*)d_in[5];
    const float* b3r = (const float*)d_in[6];
    const float* W1i = (const float*)d_in[7];
    const float* b1i = (const float*)d_in[8];
    const float* W2i = (const float*)d_in[9];
    const float* b2i = (const float*)d_in[10];
    const float* W3i = (const float*)d_in[11];
    const float* b3i = (const float*)d_in[12];
    float* out = (float*)d_out;
    float* ws  = (float*)d_ws;

    const dim3 grid(MT * NCH), block(256);
    const size_t plane = (size_t)MT * BSZ;   // floats per branch

    if (out_size >= (int)(2 * plane)) {
        // d_out = [B][M] of (re,im) float pairs
        if (ws_size >= 2 * plane * sizeof(float)) {
            rmat_mlp_mfma<0><<<grid, block, 0, stream>>>(U, W1r, b1r, W2r, b2r, W3r, b3r, ws, 0);
            rmat_mlp_mfma<0><<<grid, block, 0, stream>>>(U, W1i, b1i, W2i, b2i, W3i, b3i, ws + plane, 1);
            rmat_interleave<2><<<dim3(512), block, 0, stream>>>(ws, out);
        } else {
            rmat_mlp_mfma<1><<<grid, block, 0, stream>>>(U, W1r, b1r, W2r, b2r, W3r, b3r, out, 0);
            rmat_mlp_mfma<1><<<grid, block, 0, stream>>>(U, W1i, b1i, W2i, b2i, W3i, b3i, out, 1);
        }
    } else {
        // d_out holds B*M float32 -> real branch only, stored DIRECTLY
        // (r19: no ws round-trip, no interleave dispatch)
        rmat_mlp_mfma<2><<<grid, block, 0, stream>>>(U, W1r, b1r, W2r, b2r, W3r, b3r, out, 0);
    }
}